// Round 14
// baseline (24.374 us; speedup 1.0000x reference)
//
#include <hip/hip_runtime.h>

// Problem constants (match setup_inputs)
#define BB   2
#define CC   3
#define HH   192
#define WW   192
#define LL   19
#define PADR 9
#define HWN  (HH * WW)          // 36864
#define TAPS (LL * LL)          // 361

#define PIXB  32                 // pixels per block
#define NG    (HWN / PIXB)       // 1152 groups per kb
#define TCOLS (PIXB + LL - 1)    // 50 tile cols (float4)
#define IF4   (LL * TCOLS)       // 950 float4 of image tile per block

// DPP row_shr add step: a[i] += a[i-N] within each 16-lane row (OOB -> 0).
template <int CTRL>
__device__ __forceinline__ float dpp_add(float a) {
    int t = __builtin_amdgcn_update_dpp(0, __float_as_int(a), CTRL, 0xf, 0xf,
                                        true);
    return a + __int_as_float(t);
}

__device__ __forceinline__ int reflect_h(int y) {
    return y < 0 ? -y : (y >= HH ? 2 * HH - 2 - y : y);
}
__device__ __forceinline__ int reflect_w(int xq) {
    return xq < 0 ? -xq : (xq >= WW ? 2 * WW - 2 - xq : xq);
}

// Single fused dispatch. 512-thread block = 32 consecutive same-row pixels of
// one kb. Async-stage split (T14): ALL 23 kern-tap loads issue to registers
// FIRST (deep per-wave MLP keeps the HBM queue full), then the reflected
// packed image tile is staged from x (L2-resident) under that latency; the
// barrier drains both; the post-barrier loop is pure LDS+FMA (no VMEM).
// Compute loop otherwise identical to R12: iv ds_read_b128 with incremental
// tap->tile offset (stride-1 lane gather = conflict-free), DPP reduce.
__global__ __launch_bounds__(512) void sv_blur_f32(
    const float* __restrict__ x, const float* __restrict__ kern,
    float* __restrict__ out) {
    __shared__ float4 tile[IF4];     // 950 float4 = 15.2 KB

    int bx  = blockIdx.x;
    int kb  = bx / NG;
    int grp = bx % NG;
    int p0  = grp * PIXB;
    int h   = p0 / WW, w0 = p0 % WW;   // w0 multiple of 32: no row crossing
    int tid = threadIdx.x;

    // ---- phase 1: issue the full per-lane kern stream into registers ----
    int pp = tid >> 4;             // pixel 0..31
    int q  = tid & 15;             // lane in 16-group
    int p  = p0 + pp;
    const float* kl = kern + (size_t)(kb * HWN + p) * TAPS + q;
    float kvv[22];
#pragma unroll
    for (int j = 0; j < 22; ++j)        // taps q..q+336: always < 361
        kvv[j] = kl[j << 4];
    float kt = 0.f;
    if (q < 9) kt = kl[22 << 4];        // tail tap q+352 (exec-masked: no OOB)

    // ---- phase 2: stage packed reflected tile (x is L2-resident) ----
#pragma unroll
    for (int r = 0; r < 2; ++r) {
        int s = (r << 9) + tid;
        if (s < IF4) {
            int pr = s / TCOLS, pc = s % TCOLS;
            int oy = reflect_h(h + pr - PADR);
            int ox = reflect_w(w0 + pc - PADR);
            size_t base = (size_t)oy * WW + ox;
            float v0 = x[(size_t)(kb + 0 * BB) * HWN + base];
            float v1 = x[(size_t)(kb + 1 * BB) * HWN + base];
            float v2 = x[(size_t)(kb + 2 * BB) * HWN + base];
            tile[s] = make_float4(v0, v1, v2, 0.0f);
        }
    }
    __syncthreads();

    // ---- phase 3: pure LDS+FMA compute ----
    const float4* tb = tile + pp;
    // incremental tap coords for t = q + 16j: kj=t%19, ioff=(t/19)*50+kj
    int kj   = q;          // q <= 15 < 19
    int ioff = q;
    float a0 = 0.f, a1 = 0.f, a2 = 0.f;
#pragma unroll
    for (int j = 0; j < 22; ++j) {
        float4 iv = tb[ioff];
        a0 = fmaf(kvv[j], iv.x, a0);
        a1 = fmaf(kvv[j], iv.y, a1);
        a2 = fmaf(kvv[j], iv.z, a2);
        // t += 16: kj+16 wraps past 19 iff kj >= 3
        bool wrap = kj >= 3;
        ioff += wrap ? 47 : 16;        // +50-3 on row wrap, else +16
        kj    = wrap ? kj - 3 : kj + 16;
    }
    if (q < 9) {                        // tail: t = q+352
        float4 iv = tb[ioff];
        a0 = fmaf(kt, iv.x, a0);
        a1 = fmaf(kt, iv.y, a1);
        a2 = fmaf(kt, iv.z, a2);
    }

    // ---- 16-lane reduce on the VALU pipe (DPP row_shr adds) ----
    a0 = dpp_add<0x111>(a0); a1 = dpp_add<0x111>(a1); a2 = dpp_add<0x111>(a2);
    a0 = dpp_add<0x112>(a0); a1 = dpp_add<0x112>(a1); a2 = dpp_add<0x112>(a2);
    a0 = dpp_add<0x114>(a0); a1 = dpp_add<0x114>(a1); a2 = dpp_add<0x114>(a2);
    a0 = dpp_add<0x118>(a0); a1 = dpp_add<0x118>(a1); a2 = dpp_add<0x118>(a2);

    if (q == 15) {                     // lane 15 holds the full 16-lane sum
        out[(size_t)(kb + 0 * BB) * HWN + p] = a0;
        out[(size_t)(kb + 1 * BB) * HWN + p] = a1;
        out[(size_t)(kb + 2 * BB) * HWN + p] = a2;
    }
}

extern "C" void kernel_launch(void* const* d_in, const int* in_sizes, int n_in,
                              void* d_out, int out_size, void* d_ws, size_t ws_size,
                              hipStream_t stream) {
    const float* x    = (const float*)d_in[0];
    const float* kern = (const float*)d_in[1];
    float*       out  = (float*)d_out;
    sv_blur_f32<<<BB * NG, 512, 0, stream>>>(x, kern, out);
}

// Round 15
// 23.798 us; speedup vs baseline: 1.0242x; 1.0242x over previous
//
#include <hip/hip_runtime.h>

// Problem constants (match setup_inputs)
#define BB   2
#define CC   3
#define HH   192
#define WW   192
#define LL   19
#define PADR 9
#define HWN  (HH * WW)          // 36864
#define TAPS (LL * LL)          // 361

#define PIXB  32                 // pixels per block
#define NG    (HWN / PIXB)       // 1152 groups per kb
#define TCOLS (PIXB + LL - 1)    // 50 tile cols (float4)
#define IF4   (LL * TCOLS)       // 950 float4 of image tile per block

// DPP row_shr add step: a[i] += a[i-N] within each 16-lane row (OOB -> 0).
template <int CTRL>
__device__ __forceinline__ float dpp_add(float a) {
    int t = __builtin_amdgcn_update_dpp(0, __float_as_int(a), CTRL, 0xf, 0xf,
                                        true);
    return a + __int_as_float(t);
}

__device__ __forceinline__ int reflect_h(int y) {
    return y < 0 ? -y : (y >= HH ? 2 * HH - 2 - y : y);
}
__device__ __forceinline__ int reflect_w(int xq) {
    return xq < 0 ? -xq : (xq >= WW ? 2 * WW - 2 - xq : xq);
}

// Single fused dispatch (R12 — best measured: 23.6 us). 512-thread block =
// 32 consecutive same-row pixels of one kb. Staging: each thread builds <=2
// of the 950 packed tile float4s directly from x (3 coalesced channel dword
// loads at reflected addresses, channels j=0..2 -> slot n=kb+2j, + one
// ds_write_b128). x is 0.88 MB -> L2-resident. Compute: kv global->register
// in-loop (coalesced 64B per 16-lane group; in-loop issue keeps the HBM
// queue full across the whole phase — hoisting regressed, R13), iv
// ds_read_b128 with incremental tap->tile offset (stride-1 lane gather =
// conflict-free), DPP row_shr reduce on the VALU pipe.
__global__ __launch_bounds__(512) void sv_blur_f32(
    const float* __restrict__ x, const float* __restrict__ kern,
    float* __restrict__ out) {
    __shared__ float4 tile[IF4];     // 950 float4 = 15.2 KB

    int bx  = blockIdx.x;
    int kb  = bx / NG;
    int grp = bx % NG;
    int p0  = grp * PIXB;
    int h   = p0 / WW, w0 = p0 % WW;   // w0 multiple of 32: no row crossing
    int tid = threadIdx.x;

    // ---- stage packed reflected tile: rows h-9..h+9, cols w0-9..w0+40 ----
#pragma unroll
    for (int r = 0; r < 2; ++r) {
        int s = (r << 9) + tid;
        if (s < IF4) {
            int pr = s / TCOLS, pc = s % TCOLS;
            int oy = reflect_h(h + pr - PADR);
            int ox = reflect_w(w0 + pc - PADR);
            size_t base = (size_t)oy * WW + ox;
            float v0 = x[(size_t)(kb + 0 * BB) * HWN + base];
            float v1 = x[(size_t)(kb + 1 * BB) * HWN + base];
            float v2 = x[(size_t)(kb + 2 * BB) * HWN + base];
            tile[s] = make_float4(v0, v1, v2, 0.0f);
        }
    }
    __syncthreads();

    // ---- compute: 16 lanes per pixel, kv from global ----
    int pp = tid >> 4;             // pixel 0..31
    int q  = tid & 15;             // lane in 16-group
    int p  = p0 + pp;
    const float*  kl = kern + (size_t)(kb * HWN + p) * TAPS + q;
    const float4* tb = tile + pp;

    // incremental tap coords for t = q + 16j: kj=t%19, ioff=(t/19)*50+kj
    int kj   = q;          // q <= 15 < 19
    int ioff = q;
    float a0 = 0.f, a1 = 0.f, a2 = 0.f;
#pragma unroll
    for (int j = 0; j < 22; ++j) {     // t = q..q+336: always < 361
        float  kv = kl[j << 4];        // base+q + 16j floats (imm offset)
        float4 iv = tb[ioff];
        a0 = fmaf(kv, iv.x, a0);
        a1 = fmaf(kv, iv.y, a1);
        a2 = fmaf(kv, iv.z, a2);
        // t += 16: kj+16 wraps past 19 iff kj >= 3
        bool wrap = kj >= 3;
        ioff += wrap ? 47 : 16;        // +50-3 on row wrap, else +16
        kj    = wrap ? kj - 3 : kj + 16;
    }
    if (q < 9) {                        // tail: t = q+352 valid for q < 9
        float  kv = kl[22 << 4];
        float4 iv = tb[ioff];
        a0 = fmaf(kv, iv.x, a0);
        a1 = fmaf(kv, iv.y, a1);
        a2 = fmaf(kv, iv.z, a2);
    }

    // ---- 16-lane reduce on the VALU pipe (DPP row_shr adds) ----
    a0 = dpp_add<0x111>(a0); a1 = dpp_add<0x111>(a1); a2 = dpp_add<0x111>(a2);
    a0 = dpp_add<0x112>(a0); a1 = dpp_add<0x112>(a1); a2 = dpp_add<0x112>(a2);
    a0 = dpp_add<0x114>(a0); a1 = dpp_add<0x114>(a1); a2 = dpp_add<0x114>(a2);
    a0 = dpp_add<0x118>(a0); a1 = dpp_add<0x118>(a1); a2 = dpp_add<0x118>(a2);

    if (q == 15) {                     // lane 15 holds the full 16-lane sum
        out[(size_t)(kb + 0 * BB) * HWN + p] = a0;
        out[(size_t)(kb + 1 * BB) * HWN + p] = a1;
        out[(size_t)(kb + 2 * BB) * HWN + p] = a2;
    }
}

extern "C" void kernel_launch(void* const* d_in, const int* in_sizes, int n_in,
                              void* d_out, int out_size, void* d_ws, size_t ws_size,
                              hipStream_t stream) {
    const float* x    = (const float*)d_in[0];
    const float* kern = (const float*)d_in[1];
    float*       out  = (float*)d_out;
    sv_blur_f32<<<BB * NG, 512, 0, stream>>>(x, kern, out);
}